// Round 8
// baseline (211.365 us; speedup 1.0000x reference)
//
#include <hip/hip_runtime.h>

#define NODES 100000
#define EDGES 640000
#define DF 128
#define SCAN_B 256
#define NBLK ((NODES + SCAN_B - 1) / SCAN_B)   // 391

typedef short bf16x8 __attribute__((ext_vector_type(8)));
typedef float f32x4 __attribute__((ext_vector_type(4)));

__device__ __forceinline__ unsigned short f2bf(float f) {
    unsigned u = __builtin_bit_cast(unsigned, f);
    u += 0x7FFFu + ((u >> 16) & 1u);          // round-to-nearest-even
    return (unsigned short)(u >> 16);
}
__device__ __forceinline__ float bflo(unsigned w) { return __builtin_bit_cast(float, w << 16); }
__device__ __forceinline__ float bfhi(unsigned w) { return __builtin_bit_cast(float, w & 0xFFFF0000u); }

// ---------------------------------------------------------------- zero deg
__global__ void zero_deg(uint4* __restrict__ p) {
    const int i = blockIdx.x * blockDim.x + threadIdx.x;
    if (i < NODES / 4) p[i] = make_uint4(0u, 0u, 0u, 0u);
}

// ---------------------------------------------------------------- CSR build
__global__ void hist_kernel(const int* __restrict__ dstIdx, int* __restrict__ deg) {
    int e = blockIdx.x * blockDim.x + threadIdx.x;
    if (e < EDGES) atomicAdd(&deg[dstIdx[e]], 1);
}

__global__ __launch_bounds__(SCAN_B) void scan_blocks(const int* __restrict__ deg,
                                                      int* __restrict__ excl,
                                                      int* __restrict__ bsums) {
    __shared__ int tmp[SCAN_B];
    const int i = blockIdx.x * SCAN_B + threadIdx.x;
    const int v = (i < NODES) ? deg[i] : 0;
    tmp[threadIdx.x] = v;
    __syncthreads();
    for (int off = 1; off < SCAN_B; off <<= 1) {
        int t = 0;
        if (threadIdx.x >= off) t = tmp[threadIdx.x - off];
        __syncthreads();
        if (threadIdx.x >= off) tmp[threadIdx.x] += t;
        __syncthreads();
    }
    if (i < NODES) excl[i] = tmp[threadIdx.x] - v;
    if (threadIdx.x == SCAN_B - 1) bsums[blockIdx.x] = tmp[SCAN_B - 1];
}

__global__ __launch_bounds__(512) void scan_top(int* __restrict__ bsums) {
    __shared__ int tmp[512];
    const int i = threadIdx.x;
    const int v = (i < NBLK) ? bsums[i] : 0;
    tmp[i] = v;
    __syncthreads();
    for (int off = 1; off < 512; off <<= 1) {
        int t = 0;
        if (i >= off) t = tmp[i - off];
        __syncthreads();
        if (i >= off) tmp[i] += t;
        __syncthreads();
    }
    if (i < NBLK) bsums[i] = tmp[i] - v;
}

__global__ __launch_bounds__(SCAN_B) void scan_add(const int* __restrict__ excl,
                                                   const int* __restrict__ bsums,
                                                   int* __restrict__ offs,
                                                   int* __restrict__ cursor) {
    const int i = blockIdx.x * SCAN_B + threadIdx.x;
    if (i < NODES) {
        const int o = excl[i] + bsums[blockIdx.x];
        offs[i] = o;
        cursor[i] = o;
    }
    if (i == 0) offs[NODES] = EDGES;
}

__global__ void fill_kernel(const int* __restrict__ srcIdx,
                            const int* __restrict__ dstIdx,
                            int* __restrict__ cursor,
                            int* __restrict__ sorted_src) {
    int e = blockIdx.x * blockDim.x + threadIdx.x;
    if (e < EDGES) {
        const int d = dstIdx[e];
        const int pos = atomicAdd(&cursor[d], 1);
        sorted_src[pos] = srcIdx[e];
    }
}

// ---------------------------------------------------------------- f32 -> bf16 convert
__global__ void conv_bf16(const float4* __restrict__ in, uint4* __restrict__ out, int nchunk) {
    int i = blockIdx.x * blockDim.x + threadIdx.x;
    const int stride = gridDim.x * blockDim.x;
    for (; i < nchunk; i += stride) {
        const float4 a = in[i * 2], b = in[i * 2 + 1];
        uint4 o;
        o.x = (unsigned)f2bf(a.x) | ((unsigned)f2bf(a.y) << 16);
        o.y = (unsigned)f2bf(a.z) | ((unsigned)f2bf(a.w) << 16);
        o.z = (unsigned)f2bf(b.x) | ((unsigned)f2bf(b.y) << 16);
        o.w = (unsigned)f2bf(b.z) | ((unsigned)f2bf(b.w) << 16);
        out[i] = o;
    }
}

// ---------------------------------------------------------------- W [k][n] f32 -> Wt [n][k] bf16
__global__ void prep_w(const float* __restrict__ W1, const float* __restrict__ W2,
                       unsigned short* __restrict__ Wt1, unsigned short* __restrict__ Wt2) {
    const int idx = blockIdx.x * blockDim.x + threadIdx.x;   // 0..32767
    const float* src = (idx < 16384) ? W1 : W2;
    unsigned short* dst = (idx < 16384) ? Wt1 : Wt2;
    const int r = idx & 16383;
    const int n = r & 127, k = r >> 7;
    dst[n * 128 + k] = f2bf(src[k * 128 + n]);
}

// ---------------------------------------------------------------- FUSED: out = (x + sum_N(x)) @ Wt^T + b
// 256 thr = 4 waves, 64 nodes/block. Phase 1: gather 64 aggregated rows -> swizzled LDS A-tile.
// Phase 2: MFMA from LDS. A-tile reused as epilogue transpose buffer (extra barrier).
template <int RELU, int OUT_BF16>
__global__ __launch_bounds__(256) void gin_fused(const uint4* __restrict__ xb,
                                                 const int* __restrict__ offs,
                                                 const int* __restrict__ ssrc,
                                                 const uint4* __restrict__ Wt4,
                                                 const float* __restrict__ bias,
                                                 void* __restrict__ outp) {
    __shared__ __align__(16) unsigned char wlds[32768];   // swizzled Wt
    __shared__ __align__(16) unsigned char atile[16384];  // 64 x 256B swizzled A; reused for epilogue

    const int tid = threadIdx.x;
    // ---- stage Wt (swizzled)
    #pragma unroll
    for (int i = 0; i < 8; ++i) {
        const int c = i * 256 + tid;
        const uint4 v = Wt4[c];
        const int byte = (c * 16) ^ (((c >> 4) & 7) << 4);
        *(uint4*)(wlds + byte) = v;
    }

    const int row0 = blockIdx.x * 64;
    const int lane16 = tid & 15;
    const int nslot0 = tid >> 4;     // 0..15

    // ---- phase 1: gather; each thread handles 4 local nodes (nslot0 + 16k), 16B slice lane16
    #pragma unroll
    for (int k = 0; k < 4; ++k) {
        const int nl = nslot0 + k * 16;        // local node 0..63
        const int node = row0 + nl;
        float a[8] = {0.f, 0.f, 0.f, 0.f, 0.f, 0.f, 0.f, 0.f};
        if (node < NODES) {
            const uint4 u = xb[(size_t)node * 16 + lane16];
            a[0] += bflo(u.x); a[1] += bfhi(u.x); a[2] += bflo(u.y); a[3] += bfhi(u.y);
            a[4] += bflo(u.z); a[5] += bfhi(u.z); a[6] += bflo(u.w); a[7] += bfhi(u.w);
            const int beg = offs[node];
            const int end = offs[node + 1];
            int j = beg;
            for (; j + 4 <= end; j += 4) {
                const int s0 = ssrc[j + 0];
                const int s1 = ssrc[j + 1];
                const int s2 = ssrc[j + 2];
                const int s3 = ssrc[j + 3];
                const uint4 v0 = xb[(size_t)s0 * 16 + lane16];
                const uint4 v1 = xb[(size_t)s1 * 16 + lane16];
                const uint4 v2 = xb[(size_t)s2 * 16 + lane16];
                const uint4 v3 = xb[(size_t)s3 * 16 + lane16];
                a[0] += bflo(v0.x); a[1] += bfhi(v0.x); a[2] += bflo(v0.y); a[3] += bfhi(v0.y);
                a[4] += bflo(v0.z); a[5] += bfhi(v0.z); a[6] += bflo(v0.w); a[7] += bfhi(v0.w);
                a[0] += bflo(v1.x); a[1] += bfhi(v1.x); a[2] += bflo(v1.y); a[3] += bfhi(v1.y);
                a[4] += bflo(v1.z); a[5] += bfhi(v1.z); a[6] += bflo(v1.w); a[7] += bfhi(v1.w);
                a[0] += bflo(v2.x); a[1] += bfhi(v2.x); a[2] += bflo(v2.y); a[3] += bfhi(v2.y);
                a[4] += bflo(v2.z); a[5] += bfhi(v2.z); a[6] += bflo(v2.w); a[7] += bfhi(v2.w);
                a[0] += bflo(v3.x); a[1] += bfhi(v3.x); a[2] += bflo(v3.y); a[3] += bfhi(v3.y);
                a[4] += bflo(v3.z); a[5] += bfhi(v3.z); a[6] += bflo(v3.w); a[7] += bfhi(v3.w);
            }
            for (; j < end; ++j) {
                const uint4 v = xb[(size_t)ssrc[j] * 16 + lane16];
                a[0] += bflo(v.x); a[1] += bfhi(v.x); a[2] += bflo(v.y); a[3] += bfhi(v.y);
                a[4] += bflo(v.z); a[5] += bfhi(v.z); a[6] += bflo(v.w); a[7] += bfhi(v.w);
            }
        }
        uint4 o;
        o.x = (unsigned)f2bf(a[0]) | ((unsigned)f2bf(a[1]) << 16);
        o.y = (unsigned)f2bf(a[2]) | ((unsigned)f2bf(a[3]) << 16);
        o.z = (unsigned)f2bf(a[4]) | ((unsigned)f2bf(a[5]) << 16);
        o.w = (unsigned)f2bf(a[6]) | ((unsigned)f2bf(a[7]) << 16);
        const int byte = (nl * 256 + lane16 * 16) ^ ((nl & 7) << 4);
        *(uint4*)(atile + byte) = o;
    }

    // ---- phase 2: MFMA
    const int wv = tid >> 6;
    const int l  = tid & 63;
    const int lr = l & 15;
    const int g  = l >> 4;
    const int wrow = wv * 16;             // wave's local row base

    float bv[8];
    #pragma unroll
    for (int nt = 0; nt < 8; ++nt) bv[nt] = bias[nt * 16 + lr];

    __syncthreads();

    bf16x8 af[4];
    #pragma unroll
    for (int t = 0; t < 4; ++t) {
        const int row = wrow + lr;
        const int byte = (row * 256 + t * 64 + g * 16) ^ ((row & 7) << 4);
        af[t] = *(const bf16x8*)(atile + byte);
    }

    f32x4 acc[8];
    #pragma unroll
    for (int nt = 0; nt < 8; ++nt) acc[nt] = (f32x4)(0.f);

    #pragma unroll
    for (int t = 0; t < 4; ++t) {
        #pragma unroll
        for (int nt = 0; nt < 8; ++nt) {
            const int byte = ((nt * 16 + lr) * 256 + ((((t * 4 + g) * 16) ^ ((l & 7) << 4))));
            const bf16x8 bf = *(const bf16x8*)(wlds + byte);
            acc[nt] = __builtin_amdgcn_mfma_f32_16x16x32_bf16(af[t], bf, acc[nt], 0, 0, 0);
        }
    }

    if constexpr (OUT_BF16) {
        __syncthreads();                                   // all waves done reading atile
        unsigned char* my = atile + wv * 4096;             // reuse A-tile as transpose buffer
        #pragma unroll
        for (int nt = 0; nt < 8; ++nt) {
            #pragma unroll
            for (int r = 0; r < 4; ++r) {
                float v = acc[nt][r] + bv[nt];
                if (RELU) v = fmaxf(v, 0.f);
                const int R = g * 4 + r;
                const int byte = (R * 256 + (nt * 16 + lr) * 2) ^ ((R & 7) << 4);
                *(unsigned short*)(my + byte) = f2bf(v);
            }
        }
        __syncthreads();
        unsigned short* outh = (unsigned short*)outp;
        #pragma unroll
        for (int p = 0; p < 4; ++p) {
            const int R = p * 4 + g;
            const uint4 v = *(const uint4*)(my + ((R * 256 + lr * 16) ^ ((R & 7) << 4)));
            const int gr = row0 + wrow + R;
            if (gr < NODES) *(uint4*)(outh + (size_t)gr * DF + lr * 8) = v;
        }
    } else {
        float* outf = (float*)outp;
        #pragma unroll
        for (int nt = 0; nt < 8; ++nt) {
            #pragma unroll
            for (int r = 0; r < 4; ++r) {
                const int gr = row0 + wrow + g * 4 + r;
                float v = acc[nt][r] + bv[nt];
                if (RELU) v = fmaxf(v, 0.f);
                if (gr < NODES) outf[(size_t)gr * DF + nt * 16 + lr] = v;
            }
        }
    }
}

extern "C" void kernel_launch(void* const* d_in, const int* in_sizes, int n_in,
                              void* d_out, int out_size, void* d_ws, size_t ws_size,
                              hipStream_t stream) {
    const float* x  = (const float*)d_in[0];
    const int*   ei = (const int*)d_in[1];
    const float* W1 = (const float*)d_in[2];
    const float* b1 = (const float*)d_in[3];
    const float* W2 = (const float*)d_in[4];
    const float* b2 = (const float*)d_in[5];
    float* out = (float*)d_out;

    const int* src = ei;
    const int* dst = ei + EDGES;

    unsigned short* xb   = (unsigned short*)d_ws;                 // NODES*DF bf16
    unsigned short* hb   = xb + (size_t)NODES * DF;               // NODES*DF bf16
    unsigned short* Wt1  = hb + (size_t)NODES * DF;               // 16384
    unsigned short* Wt2  = Wt1 + 16384;                           // 16384
    int* iw = (int*)(Wt2 + 16384);
    int* deg        = iw;
    int* excl       = deg + NODES;
    int* offs       = excl + NODES;
    int* cursor     = offs + NODES + 1;
    int* bsums      = cursor + NODES;
    int* sorted_src = bsums + NBLK + 1;

    // ---- CSR build
    zero_deg<<<(NODES / 4 + 255) / 256, 256, 0, stream>>>((uint4*)deg);
    hist_kernel<<<(EDGES + 255) / 256, 256, 0, stream>>>(dst, deg);
    scan_blocks<<<NBLK, SCAN_B, 0, stream>>>(deg, excl, bsums);
    scan_top<<<1, 512, 0, stream>>>(bsums);
    scan_add<<<NBLK, SCAN_B, 0, stream>>>(excl, bsums, offs, cursor);
    fill_kernel<<<(EDGES + 255) / 256, 256, 0, stream>>>(src, dst, cursor, sorted_src);

    // ---- precompute bf16 views
    conv_bf16<<<2048, 256, 0, stream>>>((const float4*)x, (uint4*)xb, NODES * DF / 8);
    prep_w<<<128, 256, 0, stream>>>(W1, W2, Wt1, Wt2);

    const int fblocks = (NODES + 63) / 64;   // 1563

    // ---- layer 1: hb = relu((x + gather(x)) @ W1 + b1)   [bf16 out]
    gin_fused<1, 1><<<fblocks, 256, 0, stream>>>((const uint4*)xb, offs, sorted_src,
                                                 (const uint4*)Wt1, b1, hb);
    // ---- layer 2: out = (h + gather(h)) @ W2 + b2        [f32 out]
    gin_fused<0, 0><<<fblocks, 256, 0, stream>>>((const uint4*)hb, offs, sorted_src,
                                                 (const uint4*)Wt2, b2, out);
}

// Round 9
// 169.774 us; speedup vs baseline: 1.2450x; 1.2450x over previous
//
#include <hip/hip_runtime.h>

#define NODES 100000
#define EDGES 640000
#define DF 128
#define SCAN_B 256
#define NBLK ((NODES + SCAN_B - 1) / SCAN_B)   // 391

typedef short bf16x8 __attribute__((ext_vector_type(8)));
typedef float f32x4 __attribute__((ext_vector_type(4)));

__device__ __forceinline__ unsigned short f2bf(float f) {
    unsigned u = __builtin_bit_cast(unsigned, f);
    u += 0x7FFFu + ((u >> 16) & 1u);          // round-to-nearest-even
    return (unsigned short)(u >> 16);
}
__device__ __forceinline__ float bflo(unsigned w) { return __builtin_bit_cast(float, w << 16); }
__device__ __forceinline__ float bfhi(unsigned w) { return __builtin_bit_cast(float, w & 0xFFFF0000u); }

// ---------------------------------------------------------------- prep: W1/W2 transpose->bf16 + zero deg (fused, independent jobs)
__global__ void prep_all(const float* __restrict__ W1, const float* __restrict__ W2,
                         unsigned short* __restrict__ Wt1, unsigned short* __restrict__ Wt2,
                         uint4* __restrict__ deg4) {
    const int idx = blockIdx.x * blockDim.x + threadIdx.x;
    if (idx < 32768) {
        const float* src = (idx < 16384) ? W1 : W2;
        unsigned short* dst = (idx < 16384) ? Wt1 : Wt2;
        const int r = idx & 16383;
        const int n = r & 127, k = r >> 7;
        dst[n * 128 + k] = f2bf(src[k * 128 + n]);
    } else {
        const int z = idx - 32768;
        if (z < NODES / 4) deg4[z] = make_uint4(0u, 0u, 0u, 0u);
    }
}

// ---------------------------------------------------------------- CSR build
__global__ void hist_kernel(const int* __restrict__ dstIdx, int* __restrict__ deg) {
    int e = blockIdx.x * blockDim.x + threadIdx.x;
    if (e < EDGES) atomicAdd(&deg[dstIdx[e]], 1);
}

__global__ __launch_bounds__(SCAN_B) void scan_blocks(const int* __restrict__ deg,
                                                      int* __restrict__ excl,
                                                      int* __restrict__ bsums) {
    __shared__ int tmp[SCAN_B];
    const int i = blockIdx.x * SCAN_B + threadIdx.x;
    const int v = (i < NODES) ? deg[i] : 0;
    tmp[threadIdx.x] = v;
    __syncthreads();
    for (int off = 1; off < SCAN_B; off <<= 1) {
        int t = 0;
        if (threadIdx.x >= off) t = tmp[threadIdx.x - off];
        __syncthreads();
        if (threadIdx.x >= off) tmp[threadIdx.x] += t;
        __syncthreads();
    }
    if (i < NODES) excl[i] = tmp[threadIdx.x] - v;
    if (threadIdx.x == SCAN_B - 1) bsums[blockIdx.x] = tmp[SCAN_B - 1];
}

// merged scan_top+scan_add: each block reduces bsums[0..blockIdx) itself (<=391 ints)
__global__ __launch_bounds__(SCAN_B) void scan_add2(const int* __restrict__ excl,
                                                    const int* __restrict__ bsums,
                                                    int* __restrict__ offs,
                                                    int* __restrict__ cursor) {
    __shared__ int red[SCAN_B];
    int partial = 0;
    for (int b = threadIdx.x; b < blockIdx.x; b += SCAN_B) partial += bsums[b];
    red[threadIdx.x] = partial;
    __syncthreads();
    #pragma unroll
    for (int off = SCAN_B / 2; off > 0; off >>= 1) {
        if (threadIdx.x < off) red[threadIdx.x] += red[threadIdx.x + off];
        __syncthreads();
    }
    const int prefix = red[0];
    const int i = blockIdx.x * SCAN_B + threadIdx.x;
    if (i < NODES) {
        const int o = excl[i] + prefix;
        offs[i] = o;
        cursor[i] = o;
    }
    if (i == 0) offs[NODES] = EDGES;
}

__global__ void fill_kernel(const int* __restrict__ srcIdx,
                            const int* __restrict__ dstIdx,
                            int* __restrict__ cursor,
                            int* __restrict__ sorted_src) {
    int e = blockIdx.x * blockDim.x + threadIdx.x;
    if (e < EDGES) {
        const int d = dstIdx[e];
        const int pos = atomicAdd(&cursor[d], 1);
        sorted_src[pos] = srcIdx[e];
    }
}

// ---------------------------------------------------------------- GEMM: Y = A @ Wt^T  (no bias/relu; bf16 out)
// A is f32 (layer 1, converted inline) or bf16 (layer 2). 256 thr = 4 waves, 64 rows/block.
template <int A_F32>
__global__ __launch_bounds__(256) void gemm_mfma(const void* __restrict__ Ap,
                                                 const uint4* __restrict__ Wt4,
                                                 unsigned short* __restrict__ outh) {
    __shared__ __align__(16) unsigned char wlds[32768];
    __shared__ __align__(16) unsigned char epi[16384];

    const int tid = threadIdx.x;
    #pragma unroll
    for (int i = 0; i < 8; ++i) {
        const int c = i * 256 + tid;
        const uint4 v = Wt4[c];
        const int byte = (c * 16) ^ (((c >> 4) & 7) << 4);
        *(uint4*)(wlds + byte) = v;
    }

    const int wv = tid >> 6;
    const int l  = tid & 63;
    const int lr = l & 15;
    const int g  = l >> 4;
    const int row0 = blockIdx.x * 64 + wv * 16;

    int arow = row0 + lr;
    if (arow >= NODES) arow = 0;      // clamp (stores guarded)

    bf16x8 af[4];
    if constexpr (A_F32) {
        const float* Af = (const float*)Ap + (size_t)arow * DF + g * 8;
        #pragma unroll
        for (int t = 0; t < 4; ++t) {
            const float4 f0 = *(const float4*)(Af + t * 32);
            const float4 f1 = *(const float4*)(Af + t * 32 + 4);
            bf16x8 v;
            v[0] = (short)f2bf(f0.x); v[1] = (short)f2bf(f0.y);
            v[2] = (short)f2bf(f0.z); v[3] = (short)f2bf(f0.w);
            v[4] = (short)f2bf(f1.x); v[5] = (short)f2bf(f1.y);
            v[6] = (short)f2bf(f1.z); v[7] = (short)f2bf(f1.w);
            af[t] = v;
        }
    } else {
        const unsigned short* Ab = (const unsigned short*)Ap + (size_t)arow * DF + g * 8;
        #pragma unroll
        for (int t = 0; t < 4; ++t) af[t] = *(const bf16x8*)(Ab + t * 32);
    }

    f32x4 acc[8];
    #pragma unroll
    for (int nt = 0; nt < 8; ++nt) acc[nt] = (f32x4)(0.f);

    __syncthreads();

    #pragma unroll
    for (int t = 0; t < 4; ++t) {
        #pragma unroll
        for (int nt = 0; nt < 8; ++nt) {
            const int byte = ((nt * 16 + lr) * 256 + ((((t * 4 + g) * 16) ^ ((l & 7) << 4))));
            const bf16x8 bf = *(const bf16x8*)(wlds + byte);
            acc[nt] = __builtin_amdgcn_mfma_f32_16x16x32_bf16(af[t], bf, acc[nt], 0, 0, 0);
        }
    }

    // epilogue: transpose via per-wave LDS for coalesced bf16 row stores
    unsigned char* my = epi + wv * 4096;
    #pragma unroll
    for (int nt = 0; nt < 8; ++nt) {
        #pragma unroll
        for (int r = 0; r < 4; ++r) {
            const int R = g * 4 + r;
            const int byte = (R * 256 + (nt * 16 + lr) * 2) ^ ((R & 7) << 4);
            *(unsigned short*)(my + byte) = f2bf(acc[nt][r]);
        }
    }
    __syncthreads();
    #pragma unroll
    for (int p = 0; p < 4; ++p) {
        const int R = p * 4 + g;
        const uint4 v = *(const uint4*)(my + ((R * 256 + lr * 16) ^ ((R & 7) << 4)));
        const int gr = row0 + R;
        if (gr < NODES) *(uint4*)(outh + (size_t)gr * DF + lr * 8) = v;
    }
}

// ---------------------------------------------------------------- gather+bias(+relu): out[i] = y[i] + sum_N y[j] + b
// 16 lanes/node, 16B/lane, 4-way edge unroll. OUT_F32: f32 out (final layer) else bf16.
template <int RELU, int OUT_F32>
__global__ __launch_bounds__(256) void gather_bias(const uint4* __restrict__ yb,
                                                   const int* __restrict__ offs,
                                                   const int* __restrict__ ssrc,
                                                   const float* __restrict__ bias,
                                                   void* __restrict__ outp) {
    const int gid = blockIdx.x * 256 + threadIdx.x;
    const int node = gid >> 4;
    const int lane = gid & 15;
    if (node >= NODES) return;

    float a[8];
    {
        const uint4 u = yb[(size_t)node * 16 + lane];
        a[0] = bflo(u.x); a[1] = bfhi(u.x);
        a[2] = bflo(u.y); a[3] = bfhi(u.y);
        a[4] = bflo(u.z); a[5] = bfhi(u.z);
        a[6] = bflo(u.w); a[7] = bfhi(u.w);
    }
    const int beg = offs[node];
    const int end = offs[node + 1];
    int j = beg;
    for (; j + 4 <= end; j += 4) {
        const int s0 = ssrc[j + 0];
        const int s1 = ssrc[j + 1];
        const int s2 = ssrc[j + 2];
        const int s3 = ssrc[j + 3];
        const uint4 v0 = yb[(size_t)s0 * 16 + lane];
        const uint4 v1 = yb[(size_t)s1 * 16 + lane];
        const uint4 v2 = yb[(size_t)s2 * 16 + lane];
        const uint4 v3 = yb[(size_t)s3 * 16 + lane];
        a[0] += bflo(v0.x); a[1] += bfhi(v0.x); a[2] += bflo(v0.y); a[3] += bfhi(v0.y);
        a[4] += bflo(v0.z); a[5] += bfhi(v0.z); a[6] += bflo(v0.w); a[7] += bfhi(v0.w);
        a[0] += bflo(v1.x); a[1] += bfhi(v1.x); a[2] += bflo(v1.y); a[3] += bfhi(v1.y);
        a[4] += bflo(v1.z); a[5] += bfhi(v1.z); a[6] += bflo(v1.w); a[7] += bfhi(v1.w);
        a[0] += bflo(v2.x); a[1] += bfhi(v2.x); a[2] += bflo(v2.y); a[3] += bfhi(v2.y);
        a[4] += bflo(v2.z); a[5] += bfhi(v2.z); a[6] += bflo(v2.w); a[7] += bfhi(v2.w);
        a[0] += bflo(v3.x); a[1] += bfhi(v3.x); a[2] += bflo(v3.y); a[3] += bfhi(v3.y);
        a[4] += bflo(v3.z); a[5] += bfhi(v3.z); a[6] += bflo(v3.w); a[7] += bfhi(v3.w);
    }
    for (; j < end; ++j) {
        const uint4 v = yb[(size_t)ssrc[j] * 16 + lane];
        a[0] += bflo(v.x); a[1] += bfhi(v.x); a[2] += bflo(v.y); a[3] += bfhi(v.y);
        a[4] += bflo(v.z); a[5] += bfhi(v.z); a[6] += bflo(v.w); a[7] += bfhi(v.w);
    }

    // bias (+relu)
    const float4 bb0 = ((const float4*)bias)[lane * 2 + 0];
    const float4 bb1 = ((const float4*)bias)[lane * 2 + 1];
    a[0] += bb0.x; a[1] += bb0.y; a[2] += bb0.z; a[3] += bb0.w;
    a[4] += bb1.x; a[5] += bb1.y; a[6] += bb1.z; a[7] += bb1.w;
    if (RELU) {
        #pragma unroll
        for (int e = 0; e < 8; ++e) a[e] = fmaxf(a[e], 0.f);
    }

    if constexpr (OUT_F32) {
        float* of = (float*)outp + (size_t)node * DF + lane * 8;
        *(float4*)(of + 0) = make_float4(a[0], a[1], a[2], a[3]);
        *(float4*)(of + 4) = make_float4(a[4], a[5], a[6], a[7]);
    } else {
        uint4 o;
        o.x = (unsigned)f2bf(a[0]) | ((unsigned)f2bf(a[1]) << 16);
        o.y = (unsigned)f2bf(a[2]) | ((unsigned)f2bf(a[3]) << 16);
        o.z = (unsigned)f2bf(a[4]) | ((unsigned)f2bf(a[5]) << 16);
        o.w = (unsigned)f2bf(a[6]) | ((unsigned)f2bf(a[7]) << 16);
        ((uint4*)outp)[(size_t)node * 16 + lane] = o;
    }
}

extern "C" void kernel_launch(void* const* d_in, const int* in_sizes, int n_in,
                              void* d_out, int out_size, void* d_ws, size_t ws_size,
                              hipStream_t stream) {
    const float* x  = (const float*)d_in[0];
    const int*   ei = (const int*)d_in[1];
    const float* W1 = (const float*)d_in[2];
    const float* b1 = (const float*)d_in[3];
    const float* W2 = (const float*)d_in[4];
    const float* b2 = (const float*)d_in[5];
    float* out = (float*)d_out;

    const int* src = ei;
    const int* dst = ei + EDGES;

    // workspace: two bf16 node buffers (B0 = y then z, B1 = h) + weights + CSR ints
    unsigned short* B0  = (unsigned short*)d_ws;                  // NODES*DF bf16
    unsigned short* B1  = B0 + (size_t)NODES * DF;                // NODES*DF bf16
    unsigned short* Wt1 = B1 + (size_t)NODES * DF;                // 16384
    unsigned short* Wt2 = Wt1 + 16384;                            // 16384
    int* iw = (int*)(Wt2 + 16384);
    int* deg        = iw;
    int* excl       = deg + NODES;
    int* offs       = excl + NODES;
    int* cursor     = offs + NODES + 1;
    int* bsums      = cursor + NODES;
    int* sorted_src = bsums + NBLK + 1;

    // ---- prep (W transpose + deg zero) and CSR build
    prep_all<<<(32768 + NODES / 4 + 255) / 256, 256, 0, stream>>>(W1, W2, Wt1, Wt2, (uint4*)deg);
    hist_kernel<<<(EDGES + 255) / 256, 256, 0, stream>>>(dst, deg);
    scan_blocks<<<NBLK, SCAN_B, 0, stream>>>(deg, excl, bsums);
    scan_add2<<<NBLK, SCAN_B, 0, stream>>>(excl, bsums, offs, cursor);
    fill_kernel<<<(EDGES + 255) / 256, 256, 0, stream>>>(src, dst, cursor, sorted_src);

    const int mblocks = (NODES + 63) / 64;          // 1563
    const int gblocks = (NODES * 16 + 255) / 256;   // 6250

    // ---- layer 1 (commuted): y = x @ W1 ; h = relu(y_i + sum_N y_j + b1)
    gemm_mfma<1><<<mblocks, 256, 0, stream>>>((const void*)x, (const uint4*)Wt1, B0);
    gather_bias<1, 0><<<gblocks, 256, 0, stream>>>((const uint4*)B0, offs, sorted_src, b1, B1);

    // ---- layer 2 (commuted): z = h @ W2 ; out = z_i + sum_N z_j + b2
    gemm_mfma<0><<<mblocks, 256, 0, stream>>>((const void*)B1, (const uint4*)Wt2, B0);
    gather_bias<0, 1><<<gblocks, 256, 0, stream>>>((const uint4*)B0, offs, sorted_src, b2, out);
}

// Round 10
// 154.477 us; speedup vs baseline: 1.3683x; 1.0990x over previous
//
#include <hip/hip_runtime.h>

#define NODES 100000
#define EDGES 640000
#define DF 128
#define SLOT 40                 // bucket slots per node; Poisson(6.4) tail @40 ~ 3e-19/node
#define OVF_CAP 4096
#define MBLK 1563               // (NODES+63)/64 gemm blocks

typedef short bf16x8 __attribute__((ext_vector_type(8)));
typedef float f32x4 __attribute__((ext_vector_type(4)));

__device__ __forceinline__ unsigned short f2bf(float f) {
    unsigned u = __builtin_bit_cast(unsigned, f);
    u += 0x7FFFu + ((u >> 16) & 1u);          // round-to-nearest-even
    return (unsigned short)(u >> 16);
}
__device__ __forceinline__ float bflo(unsigned w) { return __builtin_bit_cast(float, w << 16); }
__device__ __forceinline__ float bfhi(unsigned w) { return __builtin_bit_cast(float, w & 0xFFFF0000u); }

// ---------------------------------------------------------------- prep: W1/W2 transpose->bf16, zero cursor + ovf_cnt
__global__ void prep_all(const float* __restrict__ W1, const float* __restrict__ W2,
                         unsigned short* __restrict__ Wt1, unsigned short* __restrict__ Wt2,
                         uint4* __restrict__ cursor4, int* __restrict__ ovf) {
    const int idx = blockIdx.x * blockDim.x + threadIdx.x;
    if (idx < 32768) {
        const float* src = (idx < 16384) ? W1 : W2;
        unsigned short* dst = (idx < 16384) ? Wt1 : Wt2;
        const int r = idx & 16383;
        const int n = r & 127, k = r >> 7;
        dst[n * 128 + k] = f2bf(src[k * 128 + n]);
    } else {
        const int z = idx - 32768;
        if (z < NODES / 4) cursor4[z] = make_uint4(0u, 0u, 0u, 0u);
        else if (z == NODES / 4) ovf[0] = 0;
    }
}

// ---------------------------------------------------------------- GEMM: Y = A @ Wt^T (bf16 out). WITH_FILL: extra blocks do bucket fill.
template <int A_F32, int WITH_FILL>
__global__ __launch_bounds__(256) void gemm_mfma(const void* __restrict__ Ap,
                                                 const uint4* __restrict__ Wt4,
                                                 unsigned short* __restrict__ outh,
                                                 const int* __restrict__ srcIdx,
                                                 const int* __restrict__ dstIdx,
                                                 int* __restrict__ cursor,
                                                 int* __restrict__ slots,
                                                 int* __restrict__ ovf) {
    __shared__ __align__(16) unsigned char wlds[32768];
    __shared__ __align__(16) unsigned char epi[16384];

    if (WITH_FILL && blockIdx.x >= MBLK) {
        // ---- bucket fill: slots[d*SLOT + pos] = src  (no hist, no scan)
        const int e = (blockIdx.x - MBLK) * 256 + threadIdx.x;
        if (e < EDGES) {
            const int d = dstIdx[e];
            const int s = srcIdx[e];
            const int pos = atomicAdd(&cursor[d], 1);
            if (pos < SLOT) {
                slots[d * SLOT + pos] = s;
            } else {
                const int k = atomicAdd(&ovf[0], 1);
                if (k < OVF_CAP) { ovf[1 + 2 * k] = d; ovf[2 + 2 * k] = s; }
            }
        }
        return;
    }

    const int tid = threadIdx.x;
    #pragma unroll
    for (int i = 0; i < 8; ++i) {
        const int c = i * 256 + tid;
        const uint4 v = Wt4[c];
        const int byte = (c * 16) ^ (((c >> 4) & 7) << 4);
        *(uint4*)(wlds + byte) = v;
    }

    const int wv = tid >> 6;
    const int l  = tid & 63;
    const int lr = l & 15;
    const int g  = l >> 4;
    const int row0 = blockIdx.x * 64 + wv * 16;

    int arow = row0 + lr;
    if (arow >= NODES) arow = 0;      // clamp (stores guarded)

    bf16x8 af[4];
    if constexpr (A_F32) {
        const float* Af = (const float*)Ap + (size_t)arow * DF + g * 8;
        #pragma unroll
        for (int t = 0; t < 4; ++t) {
            const float4 f0 = *(const float4*)(Af + t * 32);
            const float4 f1 = *(const float4*)(Af + t * 32 + 4);
            bf16x8 v;
            v[0] = (short)f2bf(f0.x); v[1] = (short)f2bf(f0.y);
            v[2] = (short)f2bf(f0.z); v[3] = (short)f2bf(f0.w);
            v[4] = (short)f2bf(f1.x); v[5] = (short)f2bf(f1.y);
            v[6] = (short)f2bf(f1.z); v[7] = (short)f2bf(f1.w);
            af[t] = v;
        }
    } else {
        const unsigned short* Ab = (const unsigned short*)Ap + (size_t)arow * DF + g * 8;
        #pragma unroll
        for (int t = 0; t < 4; ++t) af[t] = *(const bf16x8*)(Ab + t * 32);
    }

    f32x4 acc[8];
    #pragma unroll
    for (int nt = 0; nt < 8; ++nt) acc[nt] = (f32x4)(0.f);

    __syncthreads();

    #pragma unroll
    for (int t = 0; t < 4; ++t) {
        #pragma unroll
        for (int nt = 0; nt < 8; ++nt) {
            const int byte = ((nt * 16 + lr) * 256 + ((((t * 4 + g) * 16) ^ ((l & 7) << 4))));
            const bf16x8 bf = *(const bf16x8*)(wlds + byte);
            acc[nt] = __builtin_amdgcn_mfma_f32_16x16x32_bf16(af[t], bf, acc[nt], 0, 0, 0);
        }
    }

    // epilogue: transpose via per-wave LDS for coalesced bf16 row stores
    unsigned char* my = epi + wv * 4096;
    #pragma unroll
    for (int nt = 0; nt < 8; ++nt) {
        #pragma unroll
        for (int r = 0; r < 4; ++r) {
            const int R = g * 4 + r;
            const int byte = (R * 256 + (nt * 16 + lr) * 2) ^ ((R & 7) << 4);
            *(unsigned short*)(my + byte) = f2bf(acc[nt][r]);
        }
    }
    __syncthreads();
    #pragma unroll
    for (int p = 0; p < 4; ++p) {
        const int R = p * 4 + g;
        const uint4 v = *(const uint4*)(my + ((R * 256 + lr * 16) ^ ((R & 7) << 4)));
        const int gr = row0 + R;
        if (gr < NODES) *(uint4*)(outh + (size_t)gr * DF + lr * 8) = v;
    }
}

// ---------------------------------------------------------------- gather+bias(+relu): out[i] = y[i] + sum_N y[j] + b
// bucket layout: deg = min(cursor[i], SLOT); neighbors in slots[i*SLOT..]
template <int RELU, int OUT_F32>
__global__ __launch_bounds__(256) void gather_bias(const uint4* __restrict__ yb,
                                                   const int* __restrict__ cursor,
                                                   const int* __restrict__ slots,
                                                   const int* __restrict__ ovf,
                                                   const float* __restrict__ bias,
                                                   void* __restrict__ outp) {
    const int gid = blockIdx.x * 256 + threadIdx.x;
    const int node = gid >> 4;
    const int lane = gid & 15;
    if (node >= NODES) return;

    float a[8];
    {
        const uint4 u = yb[(size_t)node * 16 + lane];
        a[0] = bflo(u.x); a[1] = bfhi(u.x);
        a[2] = bflo(u.y); a[3] = bfhi(u.y);
        a[4] = bflo(u.z); a[5] = bfhi(u.z);
        a[6] = bflo(u.w); a[7] = bfhi(u.w);
    }
    const int deg = min(cursor[node], SLOT);
    const int base = node * SLOT;
    int j = 0;
    for (; j + 4 <= deg; j += 4) {
        const int s0 = slots[base + j + 0];
        const int s1 = slots[base + j + 1];
        const int s2 = slots[base + j + 2];
        const int s3 = slots[base + j + 3];
        const uint4 v0 = yb[(size_t)s0 * 16 + lane];
        const uint4 v1 = yb[(size_t)s1 * 16 + lane];
        const uint4 v2 = yb[(size_t)s2 * 16 + lane];
        const uint4 v3 = yb[(size_t)s3 * 16 + lane];
        a[0] += bflo(v0.x); a[1] += bfhi(v0.x); a[2] += bflo(v0.y); a[3] += bfhi(v0.y);
        a[4] += bflo(v0.z); a[5] += bfhi(v0.z); a[6] += bflo(v0.w); a[7] += bfhi(v0.w);
        a[0] += bflo(v1.x); a[1] += bfhi(v1.x); a[2] += bflo(v1.y); a[3] += bfhi(v1.y);
        a[4] += bflo(v1.z); a[5] += bfhi(v1.z); a[6] += bflo(v1.w); a[7] += bfhi(v1.w);
        a[0] += bflo(v2.x); a[1] += bfhi(v2.x); a[2] += bflo(v2.y); a[3] += bfhi(v2.y);
        a[4] += bflo(v2.z); a[5] += bfhi(v2.z); a[6] += bflo(v2.w); a[7] += bfhi(v2.w);
        a[0] += bflo(v3.x); a[1] += bfhi(v3.x); a[2] += bflo(v3.y); a[3] += bfhi(v3.y);
        a[4] += bflo(v3.z); a[5] += bfhi(v3.z); a[6] += bflo(v3.w); a[7] += bfhi(v3.w);
    }
    for (; j < deg; ++j) {
        const uint4 v = yb[(size_t)slots[base + j] * 16 + lane];
        a[0] += bflo(v.x); a[1] += bfhi(v.x); a[2] += bflo(v.y); a[3] += bfhi(v.y);
        a[4] += bflo(v.z); a[5] += bfhi(v.z); a[6] += bflo(v.w); a[7] += bfhi(v.w);
    }

    // overflow edges (never on this input; counter is one cached int)
    const int oc = ovf[0];
    if (oc > 0) {
        const int m = min(oc, OVF_CAP);
        for (int k = 0; k < m; ++k) {
            if (ovf[1 + 2 * k] == node) {
                const uint4 v = yb[(size_t)ovf[2 + 2 * k] * 16 + lane];
                a[0] += bflo(v.x); a[1] += bfhi(v.x); a[2] += bflo(v.y); a[3] += bfhi(v.y);
                a[4] += bflo(v.z); a[5] += bfhi(v.z); a[6] += bflo(v.w); a[7] += bfhi(v.w);
            }
        }
    }

    const float4 bb0 = ((const float4*)bias)[lane * 2 + 0];
    const float4 bb1 = ((const float4*)bias)[lane * 2 + 1];
    a[0] += bb0.x; a[1] += bb0.y; a[2] += bb0.z; a[3] += bb0.w;
    a[4] += bb1.x; a[5] += bb1.y; a[6] += bb1.z; a[7] += bb1.w;
    if (RELU) {
        #pragma unroll
        for (int e = 0; e < 8; ++e) a[e] = fmaxf(a[e], 0.f);
    }

    if constexpr (OUT_F32) {
        float* of = (float*)outp + (size_t)node * DF + lane * 8;
        *(float4*)(of + 0) = make_float4(a[0], a[1], a[2], a[3]);
        *(float4*)(of + 4) = make_float4(a[4], a[5], a[6], a[7]);
    } else {
        uint4 o;
        o.x = (unsigned)f2bf(a[0]) | ((unsigned)f2bf(a[1]) << 16);
        o.y = (unsigned)f2bf(a[2]) | ((unsigned)f2bf(a[3]) << 16);
        o.z = (unsigned)f2bf(a[4]) | ((unsigned)f2bf(a[5]) << 16);
        o.w = (unsigned)f2bf(a[6]) | ((unsigned)f2bf(a[7]) << 16);
        ((uint4*)outp)[(size_t)node * 16 + lane] = o;
    }
}

extern "C" void kernel_launch(void* const* d_in, const int* in_sizes, int n_in,
                              void* d_out, int out_size, void* d_ws, size_t ws_size,
                              hipStream_t stream) {
    const float* x  = (const float*)d_in[0];
    const int*   ei = (const int*)d_in[1];
    const float* W1 = (const float*)d_in[2];
    const float* b1 = (const float*)d_in[3];
    const float* W2 = (const float*)d_in[4];
    const float* b2 = (const float*)d_in[5];
    float* out = (float*)d_out;

    const int* src = ei;
    const int* dst = ei + EDGES;

    // workspace layout
    unsigned short* B0  = (unsigned short*)d_ws;                  // NODES*DF bf16 (y / z)
    unsigned short* B1  = B0 + (size_t)NODES * DF;                // NODES*DF bf16 (h)
    unsigned short* Wt1 = B1 + (size_t)NODES * DF;                // 16384
    unsigned short* Wt2 = Wt1 + 16384;                            // 16384
    int* cursor = (int*)(Wt2 + 16384);                            // NODES
    int* slots  = cursor + NODES;                                 // NODES*SLOT (16 MB)
    int* ovf    = slots + (size_t)NODES * SLOT;                   // 1 + 2*OVF_CAP

    // 1: W transpose + zero cursor/ovf
    prep_all<<<(32768 + NODES / 4 + 1 + 255) / 256, 256, 0, stream>>>(W1, W2, Wt1, Wt2,
                                                                      (uint4*)cursor, ovf);

    const int fillblk = (EDGES + 255) / 256;        // 2500
    const int gblocks = (NODES * 16 + 255) / 256;   // 6250

    // 2: y = x @ W1 (blocks 0..MBLK-1)  ||  bucket fill (blocks MBLK..)
    gemm_mfma<1, 1><<<MBLK + fillblk, 256, 0, stream>>>((const void*)x, (const uint4*)Wt1, B0,
                                                        src, dst, cursor, slots, ovf);
    // 3: h = relu(y_i + sum_N y_j + b1)
    gather_bias<1, 0><<<gblocks, 256, 0, stream>>>((const uint4*)B0, cursor, slots, ovf, b1, B1);
    // 4: z = h @ W2
    gemm_mfma<0, 0><<<MBLK, 256, 0, stream>>>((const void*)B1, (const uint4*)Wt2, B0,
                                              nullptr, nullptr, nullptr, nullptr, nullptr);
    // 5: out = z_i + sum_N z_j + b2
    gather_bias<0, 1><<<gblocks, 256, 0, stream>>>((const uint4*)B0, cursor, slots, ovf, b2, out);
}

// Round 11
// 145.778 us; speedup vs baseline: 1.4499x; 1.0597x over previous
//
#include <hip/hip_runtime.h>

#define NODES 100000
#define EDGES 640000
#define DF 128
#define SLOT 40                 // bucket slots/node; Poisson(6.4) tail @40 ~ 1e-19
#define OVF_CAP 4096
#define MBLK 1563               // (NODES+63)/64 gemm blocks

typedef short bf16x8 __attribute__((ext_vector_type(8)));
typedef float f32x4 __attribute__((ext_vector_type(4)));

__device__ __forceinline__ unsigned short f2bf(float f) {
    unsigned u = __builtin_bit_cast(unsigned, f);
    u += 0x7FFFu + ((u >> 16) & 1u);          // round-to-nearest-even
    return (unsigned short)(u >> 16);
}
__device__ __forceinline__ float bflo(unsigned w) { return __builtin_bit_cast(float, w << 16); }
__device__ __forceinline__ float bfhi(unsigned w) { return __builtin_bit_cast(float, w & 0xFFFF0000u); }

// ---------------------------------------------------------------- prep: W transpose->bf16, zero cursor/ovf
__global__ void prep_all(const float* __restrict__ W1, const float* __restrict__ W2,
                         unsigned short* __restrict__ Wt1, unsigned short* __restrict__ Wt2,
                         uint4* __restrict__ cursor4, int* __restrict__ ovf) {
    const int idx = blockIdx.x * blockDim.x + threadIdx.x;
    if (idx < 32768) {
        const float* src = (idx < 16384) ? W1 : W2;
        unsigned short* dst = (idx < 16384) ? Wt1 : Wt2;
        const int r = idx & 16383;
        const int n = r & 127, k = r >> 7;
        dst[n * 128 + k] = f2bf(src[k * 128 + n]);
    } else {
        const int z = idx - 32768;
        if (z < NODES / 4) cursor4[z] = make_uint4(0u, 0u, 0u, 0u);
        else if (z == NODES / 4) ovf[0] = 0;
    }
}

// ---------------------------------------------------------------- bucket fill (standalone: no LDS -> full occupancy)
__global__ void fill_bucket(const int* __restrict__ srcIdx,
                            const int* __restrict__ dstIdx,
                            int* __restrict__ cursor,
                            int* __restrict__ slots,
                            int* __restrict__ ovf) {
    const int e = blockIdx.x * blockDim.x + threadIdx.x;
    if (e < EDGES) {
        const int d = dstIdx[e];
        const int s = srcIdx[e];
        const int pos = atomicAdd(&cursor[d], 1);
        if (pos < SLOT) {
            slots[d * SLOT + pos] = s;
        } else {
            const int k = atomicAdd(&ovf[0], 1);
            if (k < OVF_CAP) { ovf[1 + 2 * k] = d; ovf[2 + 2 * k] = s; }
        }
    }
}

// ---------------------------------------------------------------- GEMM: Y = A @ Wt^T (bf16 out)
template <int A_F32>
__global__ __launch_bounds__(256) void gemm_mfma(const void* __restrict__ Ap,
                                                 const uint4* __restrict__ Wt4,
                                                 unsigned short* __restrict__ outh) {
    __shared__ __align__(16) unsigned char wlds[32768];
    __shared__ __align__(16) unsigned char epi[16384];

    const int tid = threadIdx.x;
    #pragma unroll
    for (int i = 0; i < 8; ++i) {
        const int c = i * 256 + tid;
        const uint4 v = Wt4[c];
        const int byte = (c * 16) ^ (((c >> 4) & 7) << 4);
        *(uint4*)(wlds + byte) = v;
    }

    const int wv = tid >> 6;
    const int l  = tid & 63;
    const int lr = l & 15;
    const int g  = l >> 4;
    const int row0 = blockIdx.x * 64 + wv * 16;

    int arow = row0 + lr;
    if (arow >= NODES) arow = 0;      // clamp (stores guarded)

    bf16x8 af[4];
    if constexpr (A_F32) {
        const float* Af = (const float*)Ap + (size_t)arow * DF + g * 8;
        #pragma unroll
        for (int t = 0; t < 4; ++t) {
            const float4 f0 = *(const float4*)(Af + t * 32);
            const float4 f1 = *(const float4*)(Af + t * 32 + 4);
            bf16x8 v;
            v[0] = (short)f2bf(f0.x); v[1] = (short)f2bf(f0.y);
            v[2] = (short)f2bf(f0.z); v[3] = (short)f2bf(f0.w);
            v[4] = (short)f2bf(f1.x); v[5] = (short)f2bf(f1.y);
            v[6] = (short)f2bf(f1.z); v[7] = (short)f2bf(f1.w);
            af[t] = v;
        }
    } else {
        const unsigned short* Ab = (const unsigned short*)Ap + (size_t)arow * DF + g * 8;
        #pragma unroll
        for (int t = 0; t < 4; ++t) af[t] = *(const bf16x8*)(Ab + t * 32);
    }

    f32x4 acc[8];
    #pragma unroll
    for (int nt = 0; nt < 8; ++nt) acc[nt] = (f32x4)(0.f);

    __syncthreads();

    #pragma unroll
    for (int t = 0; t < 4; ++t) {
        #pragma unroll
        for (int nt = 0; nt < 8; ++nt) {
            const int byte = ((nt * 16 + lr) * 256 + ((((t * 4 + g) * 16) ^ ((l & 7) << 4))));
            const bf16x8 bf = *(const bf16x8*)(wlds + byte);
            acc[nt] = __builtin_amdgcn_mfma_f32_16x16x32_bf16(af[t], bf, acc[nt], 0, 0, 0);
        }
    }

    // epilogue: transpose via per-wave LDS for coalesced bf16 row stores
    unsigned char* my = epi + wv * 4096;
    #pragma unroll
    for (int nt = 0; nt < 8; ++nt) {
        #pragma unroll
        for (int r = 0; r < 4; ++r) {
            const int R = g * 4 + r;
            const int byte = (R * 256 + (nt * 16 + lr) * 2) ^ ((R & 7) << 4);
            *(unsigned short*)(my + byte) = f2bf(acc[nt][r]);
        }
    }
    __syncthreads();
    #pragma unroll
    for (int p = 0; p < 4; ++p) {
        const int R = p * 4 + g;
        const uint4 v = *(const uint4*)(my + ((R * 256 + lr * 16) ^ ((R & 7) << 4)));
        const int gr = row0 + R;
        if (gr < NODES) *(uint4*)(outh + (size_t)gr * DF + lr * 8) = v;
    }
}

// ---------------------------------------------------------------- gather+bias(+relu): out[i] = y[i] + sum_N y[j] + b
template <int RELU, int OUT_F32>
__global__ __launch_bounds__(256) void gather_bias(const uint4* __restrict__ yb,
                                                   const int* __restrict__ cursor,
                                                   const int* __restrict__ slots,
                                                   const int* __restrict__ ovf,
                                                   const float* __restrict__ bias,
                                                   void* __restrict__ outp) {
    const int gid = blockIdx.x * 256 + threadIdx.x;
    const int node = gid >> 4;
    const int lane = gid & 15;
    if (node >= NODES) return;

    float a[8];
    {
        const uint4 u = yb[(size_t)node * 16 + lane];
        a[0] = bflo(u.x); a[1] = bfhi(u.x);
        a[2] = bflo(u.y); a[3] = bfhi(u.y);
        a[4] = bflo(u.z); a[5] = bfhi(u.z);
        a[6] = bflo(u.w); a[7] = bfhi(u.w);
    }
    const int deg = min(cursor[node], SLOT);
    const int base = node * SLOT;
    int j = 0;
    for (; j + 4 <= deg; j += 4) {
        const int s0 = slots[base + j + 0];
        const int s1 = slots[base + j + 1];
        const int s2 = slots[base + j + 2];
        const int s3 = slots[base + j + 3];
        const uint4 v0 = yb[(size_t)s0 * 16 + lane];
        const uint4 v1 = yb[(size_t)s1 * 16 + lane];
        const uint4 v2 = yb[(size_t)s2 * 16 + lane];
        const uint4 v3 = yb[(size_t)s3 * 16 + lane];
        a[0] += bflo(v0.x); a[1] += bfhi(v0.x); a[2] += bflo(v0.y); a[3] += bfhi(v0.y);
        a[4] += bflo(v0.z); a[5] += bfhi(v0.z); a[6] += bflo(v0.w); a[7] += bfhi(v0.w);
        a[0] += bflo(v1.x); a[1] += bfhi(v1.x); a[2] += bflo(v1.y); a[3] += bfhi(v1.y);
        a[4] += bflo(v1.z); a[5] += bfhi(v1.z); a[6] += bflo(v1.w); a[7] += bfhi(v1.w);
        a[0] += bflo(v2.x); a[1] += bfhi(v2.x); a[2] += bflo(v2.y); a[3] += bfhi(v2.y);
        a[4] += bflo(v2.z); a[5] += bfhi(v2.z); a[6] += bflo(v2.w); a[7] += bfhi(v2.w);
        a[0] += bflo(v3.x); a[1] += bfhi(v3.x); a[2] += bflo(v3.y); a[3] += bfhi(v3.y);
        a[4] += bflo(v3.z); a[5] += bfhi(v3.z); a[6] += bflo(v3.w); a[7] += bfhi(v3.w);
    }
    for (; j < deg; ++j) {
        const uint4 v = yb[(size_t)slots[base + j] * 16 + lane];
        a[0] += bflo(v.x); a[1] += bfhi(v.x); a[2] += bflo(v.y); a[3] += bfhi(v.y);
        a[4] += bflo(v.z); a[5] += bfhi(v.z); a[6] += bflo(v.w); a[7] += bfhi(v.w);
    }

    // overflow edges (count 0 on this input; one cached read)
    const int oc = ovf[0];
    if (oc > 0) {
        const int m = min(oc, OVF_CAP);
        for (int k = 0; k < m; ++k) {
            if (ovf[1 + 2 * k] == node) {
                const uint4 v = yb[(size_t)ovf[2 + 2 * k] * 16 + lane];
                a[0] += bflo(v.x); a[1] += bfhi(v.x); a[2] += bflo(v.y); a[3] += bfhi(v.y);
                a[4] += bflo(v.z); a[5] += bfhi(v.z); a[6] += bflo(v.w); a[7] += bfhi(v.w);
            }
        }
    }

    const float4 bb0 = ((const float4*)bias)[lane * 2 + 0];
    const float4 bb1 = ((const float4*)bias)[lane * 2 + 1];
    a[0] += bb0.x; a[1] += bb0.y; a[2] += bb0.z; a[3] += bb0.w;
    a[4] += bb1.x; a[5] += bb1.y; a[6] += bb1.z; a[7] += bb1.w;
    if (RELU) {
        #pragma unroll
        for (int e = 0; e < 8; ++e) a[e] = fmaxf(a[e], 0.f);
    }

    if constexpr (OUT_F32) {
        float* of = (float*)outp + (size_t)node * DF + lane * 8;
        *(float4*)(of + 0) = make_float4(a[0], a[1], a[2], a[3]);
        *(float4*)(of + 4) = make_float4(a[4], a[5], a[6], a[7]);
    } else {
        uint4 o;
        o.x = (unsigned)f2bf(a[0]) | ((unsigned)f2bf(a[1]) << 16);
        o.y = (unsigned)f2bf(a[2]) | ((unsigned)f2bf(a[3]) << 16);
        o.z = (unsigned)f2bf(a[4]) | ((unsigned)f2bf(a[5]) << 16);
        o.w = (unsigned)f2bf(a[6]) | ((unsigned)f2bf(a[7]) << 16);
        ((uint4*)outp)[(size_t)node * 16 + lane] = o;
    }
}

extern "C" void kernel_launch(void* const* d_in, const int* in_sizes, int n_in,
                              void* d_out, int out_size, void* d_ws, size_t ws_size,
                              hipStream_t stream) {
    const float* x  = (const float*)d_in[0];
    const int*   ei = (const int*)d_in[1];
    const float* W1 = (const float*)d_in[2];
    const float* b1 = (const float*)d_in[3];
    const float* W2 = (const float*)d_in[4];
    const float* b2 = (const float*)d_in[5];
    float* out = (float*)d_out;

    const int* src = ei;
    const int* dst = ei + EDGES;

    // workspace layout
    unsigned short* B0  = (unsigned short*)d_ws;                  // NODES*DF bf16 (y / z)
    unsigned short* B1  = B0 + (size_t)NODES * DF;                // NODES*DF bf16 (h)
    unsigned short* Wt1 = B1 + (size_t)NODES * DF;                // 16384
    unsigned short* Wt2 = Wt1 + 16384;                            // 16384
    int* cursor = (int*)(Wt2 + 16384);                            // NODES
    int* slots  = cursor + NODES;                                 // NODES*SLOT
    int* ovf    = slots + (size_t)NODES * SLOT;                   // 1 + 2*OVF_CAP

    // 1: W transpose + zero cursor/ovf
    prep_all<<<(32768 + NODES / 4 + 1 + 255) / 256, 256, 0, stream>>>(W1, W2, Wt1, Wt2,
                                                                      (uint4*)cursor, ovf);
    // 2: bucket fill (standalone, full occupancy)
    fill_bucket<<<(EDGES + 255) / 256, 256, 0, stream>>>(src, dst, cursor, slots, ovf);

    const int gblocks = (NODES * 16 + 255) / 256;   // 6250

    // 3: y = x @ W1
    gemm_mfma<1><<<MBLK, 256, 0, stream>>>((const void*)x, (const uint4*)Wt1, B0);
    // 4: h = relu(y_i + sum_N y_j + b1)
    gather_bias<1, 0><<<gblocks, 256, 0, stream>>>((const uint4*)B0, cursor, slots, ovf, b1, B1);
    // 5: z = h @ W2
    gemm_mfma<0><<<MBLK, 256, 0, stream>>>((const void*)B1, (const uint4*)Wt2, B0);
    // 6: out = z_i + sum_N z_j + b2
    gather_bias<0, 1><<<gblocks, 256, 0, stream>>>((const uint4*)B0, cursor, slots, ovf, b2, out);
}

// Round 12
// 144.499 us; speedup vs baseline: 1.4627x; 1.0088x over previous
//
#include <hip/hip_runtime.h>

#define NODES 100000
#define EDGES 640000
#define DF 128
#define SLOT 24                 // 96B/node bucket; Poisson(6.4) P(deg>24) ~ 1.5e-8 -> zero overflow on this input
#define OVF_CAP 4096
#define MBLK 1563               // (NODES+63)/64 gemm blocks

typedef short bf16x8 __attribute__((ext_vector_type(8)));
typedef float f32x4 __attribute__((ext_vector_type(4)));

__device__ __forceinline__ unsigned short f2bf(float f) {
    unsigned u = __builtin_bit_cast(unsigned, f);
    u += 0x7FFFu + ((u >> 16) & 1u);          // round-to-nearest-even
    return (unsigned short)(u >> 16);
}
__device__ __forceinline__ float bflo(unsigned w) { return __builtin_bit_cast(float, w << 16); }
__device__ __forceinline__ float bfhi(unsigned w) { return __builtin_bit_cast(float, w & 0xFFFF0000u); }

// ---------------------------------------------------------------- prep: W transpose->bf16, zero cursor/ovf
__global__ void prep_all(const float* __restrict__ W1, const float* __restrict__ W2,
                         unsigned short* __restrict__ Wt1, unsigned short* __restrict__ Wt2,
                         uint4* __restrict__ cursor4, int* __restrict__ ovf) {
    const int idx = blockIdx.x * blockDim.x + threadIdx.x;
    if (idx < 32768) {
        const float* src = (idx < 16384) ? W1 : W2;
        unsigned short* dst = (idx < 16384) ? Wt1 : Wt2;
        const int r = idx & 16383;
        const int n = r & 127, k = r >> 7;
        dst[n * 128 + k] = f2bf(src[k * 128 + n]);
    } else {
        const int z = idx - 32768;
        if (z < NODES / 4) cursor4[z] = make_uint4(0u, 0u, 0u, 0u);
        else if (z == NODES / 4) ovf[0] = 0;
    }
}

// ---------------------------------------------------------------- bucket fill (no LDS -> full occupancy)
__global__ void fill_bucket(const int* __restrict__ srcIdx,
                            const int* __restrict__ dstIdx,
                            int* __restrict__ cursor,
                            int* __restrict__ slots,
                            int* __restrict__ ovf) {
    const int e = blockIdx.x * blockDim.x + threadIdx.x;
    if (e < EDGES) {
        const int d = dstIdx[e];
        const int s = srcIdx[e];
        const int pos = atomicAdd(&cursor[d], 1);
        if (pos < SLOT) {
            slots[d * SLOT + pos] = s;
        } else {
            const int k = atomicAdd(&ovf[0], 1);
            if (k < OVF_CAP) { ovf[1 + 2 * k] = d; ovf[2 + 2 * k] = s; }
        }
    }
}

// ---------------------------------------------------------------- GEMM: Y = A @ Wt^T (bf16 out)
template <int A_F32>
__global__ __launch_bounds__(256) void gemm_mfma(const void* __restrict__ Ap,
                                                 const uint4* __restrict__ Wt4,
                                                 unsigned short* __restrict__ outh) {
    __shared__ __align__(16) unsigned char wlds[32768];
    __shared__ __align__(16) unsigned char epi[16384];

    const int tid = threadIdx.x;
    #pragma unroll
    for (int i = 0; i < 8; ++i) {
        const int c = i * 256 + tid;
        const uint4 v = Wt4[c];
        const int byte = (c * 16) ^ (((c >> 4) & 7) << 4);
        *(uint4*)(wlds + byte) = v;
    }

    const int wv = tid >> 6;
    const int l  = tid & 63;
    const int lr = l & 15;
    const int g  = l >> 4;
    const int row0 = blockIdx.x * 64 + wv * 16;

    int arow = row0 + lr;
    if (arow >= NODES) arow = 0;      // clamp (stores guarded)

    bf16x8 af[4];
    if constexpr (A_F32) {
        const float* Af = (const float*)Ap + (size_t)arow * DF + g * 8;
        #pragma unroll
        for (int t = 0; t < 4; ++t) {
            const float4 f0 = *(const float4*)(Af + t * 32);
            const float4 f1 = *(const float4*)(Af + t * 32 + 4);
            bf16x8 v;
            v[0] = (short)f2bf(f0.x); v[1] = (short)f2bf(f0.y);
            v[2] = (short)f2bf(f0.z); v[3] = (short)f2bf(f0.w);
            v[4] = (short)f2bf(f1.x); v[5] = (short)f2bf(f1.y);
            v[6] = (short)f2bf(f1.z); v[7] = (short)f2bf(f1.w);
            af[t] = v;
        }
    } else {
        const unsigned short* Ab = (const unsigned short*)Ap + (size_t)arow * DF + g * 8;
        #pragma unroll
        for (int t = 0; t < 4; ++t) af[t] = *(const bf16x8*)(Ab + t * 32);
    }

    f32x4 acc[8];
    #pragma unroll
    for (int nt = 0; nt < 8; ++nt) acc[nt] = (f32x4)(0.f);

    __syncthreads();

    #pragma unroll
    for (int t = 0; t < 4; ++t) {
        #pragma unroll
        for (int nt = 0; nt < 8; ++nt) {
            const int byte = ((nt * 16 + lr) * 256 + ((((t * 4 + g) * 16) ^ ((l & 7) << 4))));
            const bf16x8 bf = *(const bf16x8*)(wlds + byte);
            acc[nt] = __builtin_amdgcn_mfma_f32_16x16x32_bf16(af[t], bf, acc[nt], 0, 0, 0);
        }
    }

    // epilogue: transpose via per-wave LDS for coalesced bf16 row stores
    unsigned char* my = epi + wv * 4096;
    #pragma unroll
    for (int nt = 0; nt < 8; ++nt) {
        #pragma unroll
        for (int r = 0; r < 4; ++r) {
            const int R = g * 4 + r;
            const int byte = (R * 256 + (nt * 16 + lr) * 2) ^ ((R & 7) << 4);
            *(unsigned short*)(my + byte) = f2bf(acc[nt][r]);
        }
    }
    __syncthreads();
    #pragma unroll
    for (int p = 0; p < 4; ++p) {
        const int R = p * 4 + g;
        const uint4 v = *(const uint4*)(my + ((R * 256 + lr * 16) ^ ((R & 7) << 4)));
        const int gr = row0 + R;
        if (gr < NODES) *(uint4*)(outh + (size_t)gr * DF + lr * 8) = v;
    }
}

// ---------------------------------------------------------------- gather+bias(+relu): out[i] = y[i] + sum_N y[j] + b
template <int RELU, int OUT_F32>
__global__ __launch_bounds__(256) void gather_bias(const uint4* __restrict__ yb,
                                                   const int* __restrict__ cursor,
                                                   const int* __restrict__ slots,
                                                   const int* __restrict__ ovf,
                                                   const float* __restrict__ bias,
                                                   void* __restrict__ outp) {
    const int gid = blockIdx.x * 256 + threadIdx.x;
    const int node = gid >> 4;
    const int lane = gid & 15;
    if (node >= NODES) return;

    float a[8];
    {
        const uint4 u = yb[(size_t)node * 16 + lane];
        a[0] = bflo(u.x); a[1] = bfhi(u.x);
        a[2] = bflo(u.y); a[3] = bfhi(u.y);
        a[4] = bflo(u.z); a[5] = bfhi(u.z);
        a[6] = bflo(u.w); a[7] = bfhi(u.w);
    }
    const int deg = min(cursor[node], SLOT);
    const int base = node * SLOT;
    int j = 0;
    for (; j + 4 <= deg; j += 4) {
        const int s0 = slots[base + j + 0];
        const int s1 = slots[base + j + 1];
        const int s2 = slots[base + j + 2];
        const int s3 = slots[base + j + 3];
        const uint4 v0 = yb[(size_t)s0 * 16 + lane];
        const uint4 v1 = yb[(size_t)s1 * 16 + lane];
        const uint4 v2 = yb[(size_t)s2 * 16 + lane];
        const uint4 v3 = yb[(size_t)s3 * 16 + lane];
        a[0] += bflo(v0.x); a[1] += bfhi(v0.x); a[2] += bflo(v0.y); a[3] += bfhi(v0.y);
        a[4] += bflo(v0.z); a[5] += bfhi(v0.z); a[6] += bflo(v0.w); a[7] += bfhi(v0.w);
        a[0] += bflo(v1.x); a[1] += bfhi(v1.x); a[2] += bflo(v1.y); a[3] += bfhi(v1.y);
        a[4] += bflo(v1.z); a[5] += bfhi(v1.z); a[6] += bflo(v1.w); a[7] += bfhi(v1.w);
        a[0] += bflo(v2.x); a[1] += bfhi(v2.x); a[2] += bflo(v2.y); a[3] += bfhi(v2.y);
        a[4] += bflo(v2.z); a[5] += bfhi(v2.z); a[6] += bflo(v2.w); a[7] += bfhi(v2.w);
        a[0] += bflo(v3.x); a[1] += bfhi(v3.x); a[2] += bflo(v3.y); a[3] += bfhi(v3.y);
        a[4] += bflo(v3.z); a[5] += bfhi(v3.z); a[6] += bflo(v3.w); a[7] += bfhi(v3.w);
    }
    for (; j < deg; ++j) {
        const uint4 v = yb[(size_t)slots[base + j] * 16 + lane];
        a[0] += bflo(v.x); a[1] += bfhi(v.x); a[2] += bflo(v.y); a[3] += bfhi(v.y);
        a[4] += bflo(v.z); a[5] += bfhi(v.z); a[6] += bflo(v.w); a[7] += bfhi(v.w);
    }

    // overflow edges (count 0 on this input; one cached uniform read)
    const int oc = ovf[0];
    if (oc > 0) {
        const int m = min(oc, OVF_CAP);
        for (int k = 0; k < m; ++k) {
            if (ovf[1 + 2 * k] == node) {
                const uint4 v = yb[(size_t)ovf[2 + 2 * k] * 16 + lane];
                a[0] += bflo(v.x); a[1] += bfhi(v.x); a[2] += bflo(v.y); a[3] += bfhi(v.y);
                a[4] += bflo(v.z); a[5] += bfhi(v.z); a[6] += bflo(v.w); a[7] += bfhi(v.w);
            }
        }
    }

    const float4 bb0 = ((const float4*)bias)[lane * 2 + 0];
    const float4 bb1 = ((const float4*)bias)[lane * 2 + 1];
    a[0] += bb0.x; a[1] += bb0.y; a[2] += bb0.z; a[3] += bb0.w;
    a[4] += bb1.x; a[5] += bb1.y; a[6] += bb1.z; a[7] += bb1.w;
    if (RELU) {
        #pragma unroll
        for (int e = 0; e < 8; ++e) a[e] = fmaxf(a[e], 0.f);
    }

    if constexpr (OUT_F32) {
        float* of = (float*)outp + (size_t)node * DF + lane * 8;
        *(float4*)(of + 0) = make_float4(a[0], a[1], a[2], a[3]);
        *(float4*)(of + 4) = make_float4(a[4], a[5], a[6], a[7]);
    } else {
        uint4 o;
        o.x = (unsigned)f2bf(a[0]) | ((unsigned)f2bf(a[1]) << 16);
        o.y = (unsigned)f2bf(a[2]) | ((unsigned)f2bf(a[3]) << 16);
        o.z = (unsigned)f2bf(a[4]) | ((unsigned)f2bf(a[5]) << 16);
        o.w = (unsigned)f2bf(a[6]) | ((unsigned)f2bf(a[7]) << 16);
        ((uint4*)outp)[(size_t)node * 16 + lane] = o;
    }
}

extern "C" void kernel_launch(void* const* d_in, const int* in_sizes, int n_in,
                              void* d_out, int out_size, void* d_ws, size_t ws_size,
                              hipStream_t stream) {
    const float* x  = (const float*)d_in[0];
    const int*   ei = (const int*)d_in[1];
    const float* W1 = (const float*)d_in[2];
    const float* b1 = (const float*)d_in[3];
    const float* W2 = (const float*)d_in[4];
    const float* b2 = (const float*)d_in[5];
    float* out = (float*)d_out;

    const int* src = ei;
    const int* dst = ei + EDGES;

    // workspace layout
    unsigned short* B0  = (unsigned short*)d_ws;                  // NODES*DF bf16 (y / z)
    unsigned short* B1  = B0 + (size_t)NODES * DF;                // NODES*DF bf16 (h)
    unsigned short* Wt1 = B1 + (size_t)NODES * DF;                // 16384
    unsigned short* Wt2 = Wt1 + 16384;                            // 16384
    int* cursor = (int*)(Wt2 + 16384);                            // NODES
    int* slots  = cursor + NODES;                                 // NODES*SLOT (9.6 MB)
    int* ovf    = slots + (size_t)NODES * SLOT;                   // 1 + 2*OVF_CAP

    // 1: W transpose + zero cursor/ovf
    prep_all<<<(32768 + NODES / 4 + 1 + 255) / 256, 256, 0, stream>>>(W1, W2, Wt1, Wt2,
                                                                      (uint4*)cursor, ovf);
    // 2: bucket fill
    fill_bucket<<<(EDGES + 255) / 256, 256, 0, stream>>>(src, dst, cursor, slots, ovf);

    const int gblocks = (NODES * 16 + 255) / 256;   // 6250

    // 3: y = x @ W1
    gemm_mfma<1><<<MBLK, 256, 0, stream>>>((const void*)x, (const uint4*)Wt1, B0);
    // 4: h = relu(y_i + sum_N y_j + b1)
    gather_bias<1, 0><<<gblocks, 256, 0, stream>>>((const uint4*)B0, cursor, slots, ovf, b1, B1);
    // 5: z = h @ W2
    gemm_mfma<0><<<MBLK, 256, 0, stream>>>((const void*)B1, (const uint4*)Wt2, B0);
    // 6: out = z_i + sum_N z_j + b2
    gather_bias<0, 1><<<gblocks, 256, 0, stream>>>((const uint4*)B0, cursor, slots, ovf, b2, out);
}